// Round 16
// baseline (1349.345 us; speedup 1.0000x reference)
//
#include <hip/hip_runtime.h>
#include <hip/hip_bf16.h>
#include <cmath>
#include <stdint.h>

// Round 16: gemm_gu back to 2-ahead prefetch (3-buf, 2 barriers — r12 shape, r15-proven depth);
// mask4_kernel emits bit-planes directly (drops m4 + repack dispatch). Rest = r15.

#define BB 2
#define SS 1024
#define DT 384
#define DM 768
#define NH 12
#define DH 64
#define DFF 3072
#define NL 4
#define NROW (BB*SS)
#define EPSF 1e-6f
#define QSC 0.1803368801111244f   // 0.125 * log2(e)

typedef unsigned short u16;
typedef unsigned char u8;
typedef unsigned int u32;
typedef __attribute__((ext_vector_type(8))) short s16x8;
typedef __attribute__((ext_vector_type(4))) float f32x4;

__device__ __forceinline__ u16 f2bu(float f){
    u32 x = __float_as_uint(f);
    u32 r = (x + 0x7fffu + ((x>>16)&1u)) >> 16;   // RNE
    return (u16)r;
}
__device__ __forceinline__ u32 pk2(float lo, float hi){
    return (u32)f2bu(lo) | ((u32)f2bu(hi)<<16);
}
__device__ __forceinline__ int swz(int row, int c){
    return (row<<6) + (((((c>>3) ^ row) & 7))<<3) + (c&7);
}
__device__ __forceinline__ float rsum16(float v){
    v += __shfl_xor(v,1); v += __shfl_xor(v,2);
    v += __shfl_xor(v,4); v += __shfl_xor(v,8);
    return v;
}
#define SBAR() __builtin_amdgcn_sched_barrier(0)
#define GLDS(src,dst) __builtin_amdgcn_global_load_lds((const __attribute__((address_space(1))) u32*)(src), (__attribute__((address_space(3))) u32*)(dst), 16, 0, 0)
#define GLDS4(src,dst) __builtin_amdgcn_global_load_lds((const __attribute__((address_space(1))) u32*)(src), (__attribute__((address_space(3))) u32*)(dst), 4, 0, 0)

// ------------------------------------------------- bool-buffer normalizer (dual)
__device__ void norm_bool_body(const void* __restrict__ src, u8* __restrict__ dst, int n)
{
    __shared__ int fl[4];
    if (threadIdx.x<4) fl[threadIdx.x]=0;
    __syncthreads();
    const u32* wsrc = (const u32*)src;
    const int nw = n/4;
    int any=0, nb=0, hi=0, lo=0;
    for (int i=threadIdx.x;i<nw;i+=blockDim.x){
        u32 v=wsrc[i];
        if (!v) continue;
        any=1;
        #pragma unroll
        for (int b=0;b<4;b++){
            u32 by=(v>>(8*b))&0xffu;
            if (by>1u) nb=1;
            if (by==1u && b!=0) hi=1;
        }
        if ((v&0xffffu)==0x3f80u) lo=1;
    }
    if (any) atomicOr(&fl[0],1);
    if (nb)  atomicOr(&fl[1],1);
    if (hi)  atomicOr(&fl[2],1);
    if (lo)  atomicOr(&fl[3],1);
    __syncthreads();
    int c;
    if (!fl[0]) c=0;
    else if (!fl[1]) c = fl[2] ? 2 : 1;
    else if (fl[3]) c = 3;
    else c = 1;
    for (int i=threadIdx.x;i<n;i+=blockDim.x){
        u8 v;
        if (c==0)      v=0;
        else if (c==1) v = (((const u32*)src)[i]!=0u);
        else if (c==2) v = (((const u8*)src)[i]!=0u);
        else           v = (((const u16*)src)[i]!=0u);
        dst[i]=v;
    }
}
__global__ void norm_bool2(const void* s0, u8* d0, const void* s1, u8* d1, int n)
{
    if (blockIdx.x==0) norm_bool_body(s0,d0,n);
    else               norm_bool_body(s1,d1,n);
}

// ------------------------------------------------- pack per-token metadata + zero rs slots
__global__ void pack_meta(const int* __restrict__ node, const int* __restrict__ colx,
                          const int* __restrict__ tbl, const u8* __restrict__ pad,
                          u32* __restrict__ pm, int n, float* __restrict__ rsz, int nz)
{
    int i = blockIdx.x*256 + threadIdx.x;
    if (i<n)
        pm[i] = (u32)(node[i]&0xff) | ((u32)(colx[i]&0xff)<<8) | ((u32)(tbl[i]&0xff)<<16) | ((u32)(pad[i]&1)<<24);
    for (int z=i; z<nz; z+=gridDim.x*256) rsz[z]=0.f;
}

// ------------------------------------------------- mask bit-planes directly:
// mbp[(b<<10)+k][512B] = type t*128 + qbyte; bit j of byte qb = mask_t(q=8qb+j, k)
__global__ __launch_bounds__(256) void mask4_kernel(const u32* __restrict__ pm, const int* __restrict__ f2p,
                                                    u8* __restrict__ mbp)
{
    const int b = blockIdx.y, kg = blockIdx.x;
    const int t = threadIdx.x;
    __shared__ u32 qm[1024];
    __shared__ int qf[1024*5];
    for (int i=t;i<1024;i+=256) qm[i] = pm[b*SS+i];
    for (int i=t;i<5*1024;i+=256) qf[i] = f2p[b*SS*5 + i];
    __syncthreads();
    const int q0 = t*4;
    u32 qmv[4]; int qn[4]; int qfv[4][5];
    #pragma unroll
    for (int j=0;j<4;j++){
        qmv[j]=qm[q0+j]; qn[j]=(int)(qmv[j]&0xffu);
        #pragma unroll
        for (int f=0;f<5;f++) qfv[j][f]=qf[(q0+j)*5+f];
    }
    const int qb = t>>1;                 // byte index (8 q per byte)
    const bool hiHalf = (t&1);
    for (int kk=0;kk<16;kk++){
        const int k = kg*16+kk;
        const u32 km = qm[k];
        const int kn = (int)(km&0xffu);
        u32 outw=0;                      // byte j = 4-bit type mask for q0+j
        #pragma unroll
        for (int j=0;j<4;j++){
            const u32 qmw = qmv[j];
            const bool pv = (((qmw|km)>>24)&1u)==0u;
            u32 by=0;
            if ((((qmw^km)&0x00ffff00u)==0u) && pv) by|=1;
            if ((((qmw^km)&0xffu)==0u) && pv) by|=2;
            bool nei = (qfv[j][0]==kn)||(qfv[j][1]==kn)||(qfv[j][2]==kn)||(qfv[j][3]==kn)||(qfv[j][4]==kn)
                       ||(qn[j]==kn);
            if (nei && pv) by|=4;
            if (pv) by|=8;
            if ((q0+j)==k) by=15;
            outw |= by<<(8*j);
        }
        const u32 pw = __shfl_xor(outw, 1);
        if (!hiHalf){
            u8* dst = mbp + ((size_t)((b<<10)+k))*512 + qb;
            #pragma unroll
            for (int tt=0;tt<4;tt++){
                u32 lo4=0, hi4=0;
                #pragma unroll
                for (int j=0;j<4;j++){
                    lo4 |= ((outw>>(8*j+tt))&1u) << j;
                    hi4 |= ((pw  >>(8*j+tt))&1u) << j;
                }
                dst[tt*128] = (u8)(lo4 | (hi4<<4));
            }
        }
    }
}

// ------------------------------------------------- weight f32 [K][N] -> tiled bf16 (+gamma fold)
__global__ __launch_bounds__(256) void transpose_cvt2(const float* __restrict__ src, u16* __restrict__ dst,
                                                      int K, int N, size_t dz,
                                                      const float* __restrict__ gbase, int gmode)
{
    const int z = blockIdx.z;
    src += (size_t)z*K*N;
    dst += (size_t)z*dz;
    const float* g = nullptr;
    if (gmode==1){ int m = z&3; if (m<3) g = gbase + (size_t)((z>>4)*5 + ((z>>2)&3))*768; }
    else if (gmode==2){ g = gbase + (size_t)z*5*768; }
    const int n0 = blockIdx.x*32, k0 = blockIdx.y*64;
    __shared__ float t[64][33];
    const int tid = threadIdx.x;
    const int kr = tid>>3, n4 = (tid&7)*4;
    #pragma unroll
    for (int p=0;p<2;p++){
        const int k = p*32 + kr;
        float gk = g ? g[k0+k] : 1.f;
        float4 v = *(const float4*)(src + (size_t)(k0+k)*N + n0 + n4);
        t[k][n4]=v.x*gk; t[k][n4+1]=v.y*gk; t[k][n4+2]=v.z*gk; t[k][n4+3]=v.w*gk;
    }
    __syncthreads();
    const int n = tid>>3, ks = (tid&7)*8;
    const int ng = n0 + n;
    uint4 o;
    u32* op = (u32*)&o;
    #pragma unroll
    for (int i=0;i<4;i++)
        op[i] = pk2(t[ks+2*i][n], t[ks+2*i+1][n]);
    *(uint4*)&dst[(((size_t)(ng>>7)*(K>>6) + (k0>>6))<<13) + ((ng&127)<<6) + ks] = o;
}

// ------------------------------------------------- activation f32 [M][K] -> tiled bf16 (dual src)
__global__ __launch_bounds__(256) void cvt_tiled2(const float* __restrict__ s0, u16* __restrict__ d0,
                                                  const float* __restrict__ s1, u16* __restrict__ d1, int K)
{
    const float* src = blockIdx.y ? s1 : s0;
    u16* dst = blockIdx.y ? d1 : d0;
    const int gid = blockIdx.x*256 + threadIdx.x;
    const int base = gid*8;
    const int row = base / K, col = base - row*K;
    float4 a = *(const float4*)(src + base);
    float4 b = *(const float4*)(src + base + 4);
    uint4 o;
    o.x = pk2(a.x,a.y); o.y = pk2(a.z,a.w);
    o.z = pk2(b.x,b.y); o.w = pk2(b.z,b.w);
    *(uint4*)&dst[(((size_t)(row>>7)*(K>>6) + (col>>6))<<13) + ((row&127)<<6) + (col&63)] = o;
}

// ------------------------------------------------- BM=128 GEMM (qkv): 4-buf, 2-ahead, 1 barrier/step
__device__ __forceinline__ void stage3(const u16* aT, const u16* bT, int cb, int brow,
                                       u16* la, u16* lb, int w, int l)
{
    #pragma unroll
    for (int p=0;p<2;p++){
        const int q = p*256 + w*64 + l;
        const int row = q>>2, u = q&3;
        const int so = row*64 + cb + (((u ^ ((row>>1)&3))&3)<<3);
        GLDS(aT+so, la + p*2048 + w*512);
    }
    {
        const int q = w*64 + l;
        const int row = q>>2, u = q&3;
        const int so = (brow+row)*64 + cb + (((u ^ ((row>>1)&3))&3)<<3);
        GLDS(bT+so, lb + w*512);
    }
}

__global__ __launch_bounds__(256,3) void gemm_t(
    const u16* __restrict__ At, const u16* __restrict__ Bt,
    int K, int AMS, u16* __restrict__ qk16, u16* __restrict__ vt16,
    const float* __restrict__ rs_in)
{
    __shared__ u16 lds[4][6144];   // 48KB
    const int tid = threadIdx.x;
    const int lane = tid & 63, w = tid >> 6;
    const int cg = lane >> 4, cl = lane & 15;
    const int NT = K >> 5;
    const int n0 = blockIdx.x*64;
    const int brow = n0 & 64;
    const size_t bNb = (size_t)(n0>>7)*(K>>6);

    const u16* aB = At + ((size_t)blockIdx.y * AMS << 13);
    const u16* bB = Bt + (bNb << 13);

    f32x4 acc[2][4];
    #pragma unroll
    for (int i=0;i<2;i++)
        #pragma unroll
        for (int j=0;j<4;j++) acc[i][j] = (f32x4){0.f,0.f,0.f,0.f};

    stage3(aB, bB, 0,  brow, &lds[0][0], &lds[0][4096], w, lane);
    stage3(aB, bB, 32, brow, &lds[1][0], &lds[1][4096], w, lane);

    for (int kt=0; kt<NT; kt++){
        const int buf = kt & 3;
        if (kt+2 < NT){
            const int k2 = kt+2;
            stage3(aB + ((size_t)(k2>>1)<<13), bB + ((size_t)(k2>>1)<<13),
                   (k2&1)<<5, brow, &lds[k2&3][0], &lds[k2&3][4096], w, lane);
            asm volatile("s_waitcnt vmcnt(6)" ::: "memory");
        } else if (kt+1 < NT){
            asm volatile("s_waitcnt vmcnt(3)" ::: "memory");
        } else {
            asm volatile("s_waitcnt vmcnt(0)" ::: "memory");
        }
        SBAR(); __builtin_amdgcn_s_barrier(); SBAR();
        s16x8 af[2], bf[4];
        #pragma unroll
        for (int mt=0;mt<2;mt++){
            const int ra = w*32 + mt*16 + cl;
            af[mt] = *(const s16x8*)&lds[buf][ra*32 + (((cg ^ ((ra>>1)&3))&3)<<3)];
        }
        #pragma unroll
        for (int nt=0;nt<4;nt++){
            const int rb = nt*16 + cl;
            bf[nt] = *(const s16x8*)&lds[buf][4096 + rb*32 + (((cg ^ ((rb>>1)&3))&3)<<3)];
        }
        #pragma unroll
        for (int mt=0;mt<2;mt++)
            #pragma unroll
            for (int nt=0;nt<4;nt++)
                acc[mt][nt] = __builtin_amdgcn_mfma_f32_16x16x32_bf16(af[mt], bf[nt], acc[mt][nt], 0,0,0);
    }

    const int m0 = blockIdx.y*128;
    #pragma unroll
    for (int mt=0;mt<2;mt++){
        const int grow0 = m0 + w*32 + mt*16 + cg*4;
        float rr[4];
        #pragma unroll
        for (int j=0;j<4;j++) rr[j] = rsqrtf(rs_in[grow0+j]*(1.f/768.f) + EPSF);
        #pragma unroll
        for (int nt=0;nt<4;nt++){
            const int col = n0 + nt*16 + cl;
            if (col < 768){
                #pragma unroll
                for (int j=0;j<4;j++)
                    qk16[(size_t)(grow0+j)*1536 + col] = f2bu(acc[mt][nt][j]*rr[j]*QSC);
            } else if (col < 1536){
                #pragma unroll
                for (int j=0;j<4;j++)
                    qk16[(size_t)(grow0+j)*1536 + col] = f2bu(acc[mt][nt][j]*rr[j]);
            } else {
                const int b = grow0>>10, s0 = grow0&1023;
                const int dhg = col - 1536;
                uint2 o;
                o.x = pk2(acc[mt][nt][0]*rr[0], acc[mt][nt][1]*rr[1]);
                o.y = pk2(acc[mt][nt][2]*rr[2], acc[mt][nt][3]*rr[3]);
                *(uint2*)(vt16 + ((size_t)(b*768 + dhg)<<10) + s0) = o;
            }
        }
    }
}

// ------------------------------------------------- fused gate-up-silu GEMM: 3-buf, 2-ahead, 2 barriers
__global__ __launch_bounds__(256,3) void gemm_gu(
    const u16* __restrict__ At, const u16* __restrict__ Bg, const u16* __restrict__ Bu,
    const float* __restrict__ rs_in, u16* __restrict__ o16)
{
    __shared__ u16 lds[3][8192];
    const int tid = threadIdx.x;
    const int lane = tid & 63, w = tid >> 6;
    const int cg = lane >> 4, cl = lane & 15;
    const int NT = 24;
    const int n0 = blockIdx.x*64;
    const int brow = n0 & 64;
    const size_t bNb = (size_t)(n0>>7)*12;

    const u16* aB = At + ((size_t)blockIdx.y * 12 << 13);
    const u16* gB = Bg + (bNb << 13);
    const u16* uB = Bu + (bNb << 13);

    f32x4 accg[2][4], accu[2][4];
    #pragma unroll
    for (int i=0;i<2;i++)
        #pragma unroll
        for (int j=0;j<4;j++){ accg[i][j] = (f32x4){0.f,0.f,0.f,0.f}; accu[i][j] = (f32x4){0.f,0.f,0.f,0.f}; }

    #define STAGE_GU(kt2, cb, buf) { \
        const u16* a_ = aB + ((size_t)(kt2)<<13); \
        const u16* g_ = gB + ((size_t)(kt2)<<13); \
        const u16* u_ = uB + ((size_t)(kt2)<<13); \
        _Pragma("unroll") \
        for (int p=0;p<2;p++){ \
            const int q = p*256 + w*64 + lane; \
            const int row = q>>2, uu = q&3; \
            const int so = row*64 + (cb) + (((uu ^ ((row>>1)&3))&3)<<3); \
            GLDS(a_+so, &lds[buf][0] + p*2048 + w*512); \
        } \
        { \
            const int q = w*64 + lane; \
            const int row = q>>2, uu = q&3; \
            const int so = (brow+row)*64 + (cb) + (((uu ^ ((row>>1)&3))&3)<<3); \
            GLDS(g_+so, &lds[buf][4096] + w*512); \
            GLDS(u_+so, &lds[buf][6144] + w*512); \
        } }

    STAGE_GU(0, 0,  0);
    STAGE_GU(0, 32, 1);

    for (int kt=0; kt<NT; kt++){
        const int buf = kt % 3;
        if (kt+2 < NT){
            const int k2 = kt+2;
            STAGE_GU(k2>>1, (k2&1)<<5, k2%3);
            asm volatile("s_waitcnt vmcnt(8)" ::: "memory");
        } else if (kt+1 < NT){
            asm volatile("s_waitcnt vmcnt(4)" ::: "memory");
        } else {
            asm volatile("s_waitcnt vmcnt(0)" ::: "memory");
        }
        SBAR(); __builtin_amdgcn_s_barrier(); SBAR();
        s16x8 af[2], bg[4], bu[4];
        #pragma unroll
        for (int mt=0;mt<2;mt++){
            const int ra = w*32 + mt*16 + cl;
            af[mt] = *(const s16x8*)&lds[buf][ra*32 + (((cg ^ ((ra>>1)&3))&3)<<3)];
        }
        #pragma unroll
        for (int nt=0;nt<4;nt++){
            const int rb = nt*16 + cl;
            const int sw = (((cg ^ ((rb>>1)&3))&3)<<3);
            bg[nt] = *(const s16x8*)&lds[buf][4096 + rb*32 + sw];
            bu[nt] = *(const s16x8*)&lds[buf][6144 + rb*32 + sw];
        }
        #pragma unroll
        for (int mt=0;mt<2;mt++)
            #pragma unroll
            for (int nt=0;nt<4;nt++){
                accg[mt][nt] = __builtin_amdgcn_mfma_f32_16x16x32_bf16(af[mt], bg[nt], accg[mt][nt], 0,0,0);
                accu[mt][nt] = __builtin_amdgcn_mfma_f32_16x16x32_bf16(af[mt], bu[nt], accu[mt][nt], 0,0,0);
            }
        SBAR(); __builtin_amdgcn_s_barrier(); SBAR();   // seal reads before next stage overwrites
    }

    const int m0 = blockIdx.y*128;
    #pragma unroll
    for (int mt=0;mt<2;mt++){
        const int grow0 = m0 + w*32 + mt*16 + cg*4;
        float rr[4];
        #pragma unroll
        for (int j=0;j<4;j++) rr[j] = rsqrtf(rs_in[grow0+j]*(1.f/768.f) + EPSF);
        #pragma unroll
        for (int nt=0;nt<4;nt++){
            const int col = n0 + nt*16 + cl;
            const size_t tb = (((size_t)(grow0>>7)*48 + (col>>6))<<13) + (col&63);
            #pragma unroll
            for (int j=0;j<4;j++){
                float g = accg[mt][nt][j]*rr[j];
                float u = accu[mt][nt][j]*rr[j];
                float s = g/(1.f+__expf(-g))*u;
                o16[tb + (((grow0+j)&127)<<6)] = f2bu(s);
            }
        }
    }
}

// ------------------------------------------------- BM=64 GEMM: 4-buf, 2-ahead, 1 barrier/step
__device__ __forceinline__ void stage64(const u16* aT, int arow, const u16* bT, int brow, int cb,
                                        u16* la, u16* lb, int w, int l)
{
    const int q = w*64 + l;
    const int row = q>>2, u = q&3;
    const int sw = (((u ^ ((row>>1)&3))&3)<<3);
    GLDS(aT + (arow+row)*64 + cb + sw, la + w*512);
    GLDS(bT + (brow+row)*64 + cb + sw, lb + w*512);
}

__global__ __launch_bounds__(256,4) void gemm_t64(
    const u16* __restrict__ At, const u16* __restrict__ Bt, float* __restrict__ C,
    int N, int K, int AMS, int flags, const float* __restrict__ bias,
    u16* __restrict__ o16, float* __restrict__ rs_out)
{
    __shared__ u16 lds[4][4096];   // 32KB
    const int tid = threadIdx.x;
    const int lane = tid & 63, w = tid >> 6;
    const int cg = lane >> 4, cl = lane & 15;
    const int NT = K >> 5;
    const int n0 = blockIdx.x*64;
    const int m0 = blockIdx.y*64;
    const int brow = n0 & 64, arow = m0 & 64;

    const u16* aB = At + ((size_t)(m0>>7) * AMS << 13);
    const u16* bB = Bt + ((size_t)(n0>>7) * (K>>6) << 13);

    f32x4 acc[4];
    #pragma unroll
    for (int j=0;j<4;j++) acc[j] = (f32x4){0.f,0.f,0.f,0.f};

    stage64(aB, arow, bB, brow, 0,  &lds[0][0], &lds[0][2048], w, lane);
    stage64(aB, arow, bB, brow, 32, &lds[1][0], &lds[1][2048], w, lane);

    for (int kt=0; kt<NT; kt++){
        const int buf = kt & 3;
        if (kt+2 < NT){
            const int k2 = kt+2;
            stage64(aB + ((size_t)(k2>>1)<<13), arow, bB + ((size_t)(k2>>1)<<13), brow,
                    (k2&1)<<5, &lds[k2&3][0], &lds[k2&3][2048], w, lane);
            asm volatile("s_waitcnt vmcnt(4)" ::: "memory");
        } else if (kt+1 < NT){
            asm volatile("s_waitcnt vmcnt(2)" ::: "memory");
        } else {
            asm volatile("s_waitcnt vmcnt(0)" ::: "memory");
        }
        SBAR(); __builtin_amdgcn_s_barrier(); SBAR();
        const int ra = w*16 + cl;
        s16x8 af = *(const s16x8*)&lds[buf][ra*32 + (((cg ^ ((ra>>1)&3))&3)<<3)];
        s16x8 bf[4];
        #pragma unroll
        for (int nt=0;nt<4;nt++){
            const int rb = nt*16 + cl;
            bf[nt] = *(const s16x8*)&lds[buf][2048 + rb*32 + (((cg ^ ((rb>>1)&3))&3)<<3)];
        }
        #pragma unroll
        for (int nt=0;nt<4;nt++)
            acc[nt] = __builtin_amdgcn_mfma_f32_16x16x32_bf16(af, bf[nt], acc[nt], 0,0,0);
    }

    const int grow0 = m0 + w*16 + cg*4;
    const bool do_acc = (flags&1), do_bias = (flags&2);
    float tmp[4][4];
    #pragma unroll
    for (int nt=0;nt<4;nt++){
        const int col = n0 + nt*16 + cl;
        float bv = do_bias ? bias[col] : 0.f;
        #pragma unroll
        for (int j=0;j<4;j++){
            float v = acc[nt][j] + bv;
            float* cp = C + (size_t)(grow0+j)*N + col;
            if (do_acc) v += *cp;
            *cp = v;
            tmp[nt][j] = v;
        }
    }
    if (o16){
        #pragma unroll
        for (int nt=0;nt<4;nt++){
            const int col = n0 + nt*16 + cl;
            const size_t tb = (((size_t)(grow0>>7)*12 + (col>>6))<<13) + (col&63);
            #pragma unroll
            for (int j=0;j<4;j++)
                o16[tb + (((grow0+j)&127)<<6)] = f2bu(tmp[nt][j]);
        }
    }
    if (rs_out){
        #pragma unroll
        for (int j=0;j<4;j++){
            float s = tmp[0][j]*tmp[0][j] + tmp[1][j]*tmp[1][j]
                    + tmp[2][j]*tmp[2][j] + tmp[3][j]*tmp[3][j];
            s = rsum16(s);
            if (cl==0) atomicAdd(rs_out + grow0 + j, s);
        }
    }
}

// ------------------------------------------------- MFMA flash attention: 3-buf K/V/M, 1 barrier/chunk
__global__ __launch_bounds__(256,2) void attn_mfma5(
    const u16* __restrict__ qk16, const u16* __restrict__ vt16,
    const u8* __restrict__ mbp, int mt,
    u16* __restrict__ ob16)
{
    const int bh = blockIdx.y;
    const int b = bh / NH, h = bh % NH;
    const int q0 = blockIdx.x * 64;
    const int tid = threadIdx.x;
    const int w = tid>>6, lane = tid&63, cg = lane>>4, cl = lane&15;
    const int srow = lane>>3;
    const int sseg = (lane&7) ^ srow;

    __shared__ u16 Ks[3][4096], Vt[3][4096], Ps[4096];
    __shared__ u8 Ms[3][512];

    s16x8 qa0, qa1;
    {
        const u16* qrow = qk16 + (size_t)(b*SS+q0 + w*16 + cl)*1536 + h*64;
        qa0 = *(const s16x8*)(qrow + cg*8);
        qa1 = *(const s16x8*)(qrow + 32 + cg*8);
        asm volatile("" :: "v"(*(const f32x4*)&qa0), "v"(*(const f32x4*)&qa1));
    }

    const u16* kbase = qk16 + (size_t)(b*SS)*1536 + 768 + h*64;
    const u16* vbase = vt16 + ((size_t)(b*768 + h*64)<<10);
    const u8* mrow0 = mbp + ((size_t)(b<<10))*512 + mt*128 + (q0>>3);

    #pragma unroll
    for (int p=0;p<2;p++){
        const int row = p*32 + w*8 + srow;
        GLDS(kbase + (size_t)row*1536 + sseg*8, Ks[0] + p*2048 + w*512);
        GLDS(vbase + ((size_t)row<<10) + sseg*8, Vt[0] + p*2048 + w*512);
    }
    if (lane < 32){
        const int krow = w*16 + (lane>>1);
        GLDS4(mrow0 + (size_t)krow*512 + (lane&1)*4, Ms[0] + w*128);
    }

    f32x4 o[4];
    #pragma unroll
    for (int nt=0;nt<4;nt++) o[nt] = (f32x4){0.f,0.f,0.f,0.f};
    float lsum[4] = {0.f,0.f,0.f,0.f};

    for (int kc=0;kc<16;kc++){
        const int buf = kc % 3;
        if (kc < 15){
            const int nb = (kc+1) % 3;
            const int kn0 = kc*64 + 64;
            #pragma unroll
            for (int p=0;p<2;p++){
                const int row = p*32 + w*8 + srow;
                GLDS(kbase + (size_t)(kn0+row)*1536 + sseg*8, Ks[nb] + p*2048 + w*512);
                GLDS(vbase + ((size_t)row<<10) + kn0 + sseg*8, Vt[nb] + p*2048 + w*512);
            }
            if (lane < 32){
                const int krow = kn0 + w*16 + (lane>>1);
                GLDS4(mrow0 + (size_t)krow*512 + (lane&1)*4, Ms[nb] + w*128);
            }
            asm volatile("s_waitcnt vmcnt(5)" ::: "memory");
        } else {
            asm volatile("s_waitcnt vmcnt(0)" ::: "memory");
        }
        SBAR(); __builtin_amdgcn_s_barrier(); SBAR();

        f32x4 sc[4];
        #pragma unroll
        for (int nt=0;nt<4;nt++) sc[nt] = (f32x4){0.f,0.f,0.f,0.f};
        __builtin_amdgcn_s_setprio(1);
        #pragma unroll
        for (int nt=0;nt<4;nt++){
            s16x8 kb0 = *(const s16x8*)&Ks[buf][swz(nt*16+cl, cg*8)];
            sc[nt] = __builtin_amdgcn_mfma_f32_16x16x32_bf16(qa0, kb0, sc[nt], 0,0,0);
        }
        #pragma unroll
        for (int nt=0;nt<4;nt++){
            s16x8 kb1 = *(const s16x8*)&Ks[buf][swz(nt*16+cl, 32+cg*8)];
            sc[nt] = __builtin_amdgcn_mfma_f32_16x16x32_bf16(qa1, kb1, sc[nt], 0,0,0);
        }
        __builtin_amdgcn_s_setprio(0);

        float pP[4][4];
        const int qb = 2*w + (cg>>1);
        const int bsh = (cg&1)*4;
        #pragma unroll
        for (int nt=0;nt<4;nt++){
            const u32 mrow = Ms[buf][(nt*16+cl)*8 + qb];
            #pragma unroll
            for (int j=0;j<4;j++){
                float pe = exp2f(fminf(sc[nt][j], 100.f));
                pe = ((mrow >> (bsh+j)) & 1u) ? pe : 0.f;
                pP[nt][j] = pe;
                lsum[j] += pe;
            }
        }

        #pragma unroll
        for (int nt=0;nt<4;nt++)
            #pragma unroll
            for (int j=0;j<4;j++)
                Ps[swz(w*16+cg*4+j, nt*16+cl)] = f2bu(pP[nt][j]);

        __builtin_amdgcn_s_setprio(1);
        #pragma unroll
        for (int ks=0;ks<2;ks++){
            s16x8 pa = *(const s16x8*)&Ps[swz(w*16+cl, ks*32+cg*8)];
            #pragma unroll
            for (int nt=0;nt<4;nt++){
                s16x8 vb = *(const s16x8*)&Vt[buf][swz(nt*16+cl, ks*32+cg*8)];
                o[nt] = __builtin_amdgcn_mfma_f32_16x16x32_bf16(pa, vb, o[nt], 0,0,0);
            }
        }
        __builtin_amdgcn_s_setprio(0);
    }

    #pragma unroll
    for (int j=0;j<4;j++){
        const float inv = 1.f/rsum16(lsum[j]);
        const int row = b*SS + q0 + w*16 + cg*4 + j;
        const size_t rb = ((size_t)(row>>7)*12 + h)*8192 + ((row&127)<<6);
        #pragma unroll
        for (int nt=0;nt<4;nt++)
            ob16[rb + nt*16 + cl] = f2bu(o[nt][j]*inv);
    }
}

// ------------------------------------------------- encode fuse
__global__ __launch_bounds__(256) void fuse_encode(
    const float* __restrict__ cnbuf, const float* __restrict__ textbuf,
    const float* __restrict__ numv, const float* __restrict__ dtv, const float* __restrict__ boolv,
    const float* __restrict__ Wnum, const float* __restrict__ bnum,
    const float* __restrict__ Wdt, const float* __restrict__ bdt,
    const float* __restrict__ Wbool, const float* __restrict__ bbool,
    const float* __restrict__ gcn, const float* __restrict__ gnum, const float* __restrict__ gtext,
    const float* __restrict__ gdt, const float* __restrict__ gbool,
    const float* __restrict__ memb, const int* __restrict__ stypes, const u8* __restrict__ masks,
    float* __restrict__ x, u16* __restrict__ xt16, float* __restrict__ rs0)
{
    const int row = blockIdx.x;
    const int t = threadIdx.x;
    __shared__ float red[256];

    float cn3[3]; float ss=0.f;
    #pragma unroll
    for (int j=0;j<3;j++){
        cn3[j] = cnbuf[(size_t)row*DM + t + j*256];
        ss += cn3[j]*cn3[j];
    }
    red[t]=ss; __syncthreads();
    for (int s=128;s>0;s>>=1){ if(t<s) red[t]+=red[t+s]; __syncthreads(); }
    {
        float r = rsqrtf(red[0]/(float)DM + EPSF);
        #pragma unroll
        for (int j=0;j<3;j++) cn3[j] *= r*gcn[t+j*256];
    }
    __syncthreads();

    const int st = stypes[row];
    float val[3]; ss=0.f;
    if (st==1){
        #pragma unroll
        for (int j=0;j<3;j++){
            val[j] = textbuf[(size_t)row*DM + t + j*256];
            ss += val[j]*val[j];
        }
    } else {
        const float* Wp = (st==0)?Wnum:((st==2)?Wdt:Wbool);
        const float* bp = (st==0)?bnum:((st==2)?bdt:bbool);
        const float* vp = (st==0)?numv:((st==2)?dtv:boolv);
        float v = vp[row];
        #pragma unroll
        for (int j=0;j<3;j++){
            int e=t+j*256;
            val[j] = v*Wp[e] + bp[e];
            ss += val[j]*val[j];
        }
    }
    red[t]=ss; __syncthreads();
    for (int s=128;s>0;s>>=1){ if(t<s) red[t]+=red[t+s]; __syncthreads(); }
    const float* gp = (st==0)?gnum:((st==1)?gtext:((st==2)?gdt:gbool));
    float r2 = rsqrtf(red[0]/(float)DM + EPSF);
    bool mk = masks[row]!=0;
    float xv[3]; float sx=0.f;
    #pragma unroll
    for (int j=0;j<3;j++){
        int e=t+j*256;
        float vv = val[j]*r2*gp[e];
        if (mk) vv = memb[st*DM+e];
        xv[j] = vv + cn3[j];
        x[(size_t)row*DM+e] = xv[j];
        sx += xv[j]*xv[j];
    }
    __syncthreads();
    red[t]=sx; __syncthreads();
    for (int s=128;s>0;s>>=1){ if(t<s) red[t]+=red[t+s]; __syncthreads(); }
    if (t==0) rs0[row] = red[0];
    const size_t mb = (size_t)(row>>7)*12;
    const int rr = (row&127)<<6;
    #pragma unroll
    for (int j=0;j<3;j++){
        const int c = t + j*256;
        xt16[((mb + (c>>6))<<13) + rr + (c&63)] = f2bu(xv[j]);
    }
}

// ------------------------------------------------- final rms + 3 scalar heads; h -> tiled bf16
__global__ __launch_bounds__(256) void decode2(
    const float* __restrict__ x, const float* __restrict__ gout,
    const float* __restrict__ Wn, const float* __restrict__ bn,
    const float* __restrict__ Wd, const float* __restrict__ bd,
    const float* __restrict__ Wb, const float* __restrict__ bb,
    float* __restrict__ out, u16* __restrict__ h16)
{
    const int row = blockIdx.x;
    const int t = threadIdx.x;
    __shared__ float h[DM];
    __shared__ float red[256];
    const float* xr = x + (size_t)row*DM;
    float v0=xr[t], v1=xr[t+256], v2=xr[t+512];
    red[t]=v0*v0+v1*v1+v2*v2; __syncthreads();
    for (int s=128;s>0;s>>=1){ if(t<s) red[t]+=red[t+s]; __syncthreads(); }
    float r = rsqrtf(red[0]/(float)DM + EPSF);
    float h0 = v0*r*gout[t], h1 = v1*r*gout[t+256], h2 = v2*r*gout[t+512];
    h[t]=h0; h[t+256]=h1; h[t+512]=h2;
    const size_t mb = (size_t)(row>>7)*12;
    const int rr = (row&127)<<6;
    #pragma unroll
    for (int j=0;j<3;j++){
        const int c = t + j*256;
        const float v = (j==0?h0:(j==1?h1:h2));
        h16[((mb + (c>>6))<<13) + rr + (c&63)] = f2bu(v);
    }
    __syncthreads();

    float pn=0.f,pd=0.f,pb=0.f;
    for (int k=t;k<DM;k+=256){ float hv=h[k]; pn+=hv*Wn[k]; pd+=hv*Wd[k]; pb+=hv*Wb[k]; }
    red[t]=pn; __syncthreads();
    for (int s=128;s>0;s>>=1){ if(t<s) red[t]+=red[t+s]; __syncthreads(); }
    float tn=red[0]; __syncthreads();
    red[t]=pd; __syncthreads();
    for (int s=128;s>0;s>>=1){ if(t<s) red[t]+=red[t+s]; __syncthreads(); }
    float td=red[0]; __syncthreads();
    red[t]=pb; __syncthreads();
    for (int s=128;s>0;s>>=1){ if(t<s) red[t]+=red[t+s]; __syncthreads(); }
    float tb=red[0];
    if (t==0){
        out[row]          = tn + bn[0];
        out[NROW + row]   = td + bd[0];
        out[2*NROW + row] = tb + bb[0];
    }
}

// ---------------------------------------------------------------- launcher
extern "C" void kernel_launch(void* const* d_in, const int* in_sizes, int n_in,
                              void* d_out, int out_size, void* d_ws, size_t ws_size,
                              hipStream_t stream)
{
    const float* numv   = (const float*)d_in[0];
    const float* dtval  = (const float*)d_in[1];
    const float* boolv  = (const float*)d_in[2];
    const float* textv  = (const float*)d_in[3];
    const float* cnamev = (const float*)d_in[4];
    const float* Wcn=(const float*)d_in[5];  const float* bcn=(const float*)d_in[6];
    const float* Wnum=(const float*)d_in[7]; const float* bnum=(const float*)d_in[8];
    const float* Wtext=(const float*)d_in[9];const float* btext=(const float*)d_in[10];
    const float* Wdt=(const float*)d_in[11]; const float* bdt=(const float*)d_in[12];
    const float* Wbool=(const float*)d_in[13];const float* bbool=(const float*)d_in[14];
    const float* gcn=(const float*)d_in[15]; const float* gnum=(const float*)d_in[16];
    const float* gtext=(const float*)d_in[17];const float* gdt=(const float*)d_in[18];
    const float* gbool=(const float*)d_in[19];
    const float* memb=(const float*)d_in[20];
    const float* norms_all=(const float*)d_in[21];
    const float* attw_all=(const float*)d_in[22];
    const float* up_all=(const float*)d_in[23];
    const float* gate_all=(const float*)d_in[24];
    const float* down_all=(const float*)d_in[25];
    const float* gout=(const float*)d_in[26];
    const float* Wdn=(const float*)d_in[27]; const float* bdn=(const float*)d_in[28];
    const float* Wdd=(const float*)d_in[29]; const float* bdd=(const float*)d_in[30];
    const float* Wdb=(const float*)d_in[31]; const float* bdb=(const float*)d_in[32];
    const float* Wdtx=(const float*)d_in[33];const float* bdtx=(const float*)d_in[34];
    const int* node=(const int*)d_in[35];
    const int* tbl =(const int*)d_in[36];
    const int* colx=(const int*)d_in[37];
    const int* f2p =(const int*)d_in[38];
    const int* styp=(const int*)d_in[39];

    const size_t SA = (size_t)768*768;
    const size_t SG = (size_t)768*3072;
    const size_t SC = (size_t)384*768;
    const size_t NX = (size_t)NROW*DM;

    u8* base = (u8*)d_ws;
    float* x  = (float*)base;
    u16* xt16 = (u16*)(base + 6291456);
    u16* ob16 = (u16*)(base + 9437184);
    u16* qk16 = (u16*)(base + 12582912);
    u16* vt16 = (u16*)(base + 18874368);
    u16* gu16 = (u16*)(base + 22020096);
    u16* wA   = (u16*)(base + 47185920);
    u16* wGU  = wA + 64*SA;
    u16* wD   = wGU + 8*SG;
    u16* wCN  = wD + 4*SG;
    u16* wTX  = wCN + SC;
    u16* wDX  = wTX + SC;
    u8* nmask = (u8*)(wDX + SC);
    u8* npad  = nmask + NROW;
    u32* pmeta = (u32*)(npad + NROW + 64);
    float* rsbuf = (float*)(pmeta + NROW);     // 21 slots x 2048
    u8* mbp = (u8*)(rsbuf + 21*2048);          // 1 MB bit-planes

    // encode-phase aliases
    u16* cnT16   = qk16;
    u16* textT16 = vt16;
    float* cnbuf   = (float*)gu16;
    float* textbuf = cnbuf + NX;

    float* out = (float*)d_out;

    norm_bool2<<<2,256,0,stream>>>(d_in[40], nmask, d_in[41], npad, NROW);
    pack_meta<<<8,256,0,stream>>>(node, colx, tbl, npad, pmeta, NROW, rsbuf, 21*2048);
    mask4_kernel<<<dim3(64,2),256,0,stream>>>(pmeta, f2p, mbp);

    // weight prep (tiled bf16; gamma folded)
    transpose_cvt2<<<dim3(24,12,64),256,0,stream>>>(attw_all, wA, 768, 768, SA, norms_all, 1);
    transpose_cvt2<<<dim3(96,12,4),256,0,stream>>>(gate_all, wGU,      768, 3072, 2*SG, norms_all + 4*768, 2);
    transpose_cvt2<<<dim3(96,12,4),256,0,stream>>>(up_all,   wGU + SG, 768, 3072, 2*SG, norms_all + 4*768, 2);
    transpose_cvt2<<<dim3(24,48,4),256,0,stream>>>(down_all, wD, 3072, 768, SG, nullptr, 0);
    transpose_cvt2<<<dim3(24,6,1),256,0,stream>>>(Wcn,   wCN, 384, 768, 0, nullptr, 0);
    transpose_cvt2<<<dim3(24,6,1),256,0,stream>>>(Wtext, wTX, 384, 768, 0, nullptr, 0);
    transpose_cvt2<<<dim3(12,12,1),256,0,stream>>>(Wdtx, wDX, 768, 384, 0, nullptr, 0);

    // encode
    cvt_tiled2<<<dim3(384,2),256,0,stream>>>(cnamev, cnT16, textv, textT16, 384);
    gemm_t64<<<dim3(12,32),256,0,stream>>>(cnT16,   wCN, cnbuf,   768, 384, 6, 2, bcn,   nullptr, nullptr);
    gemm_t64<<<dim3(12,32),256,0,stream>>>(textT16, wTX, textbuf, 768, 384, 6, 2, btext, nullptr, nullptr);
    fuse_encode<<<NROW,256,0,stream>>>(cnbuf, textbuf, numv, dtval, boolv,
        Wnum,bnum,Wdt,bdt,Wbool,bbool, gcn,gnum,gtext,gdt,gbool,
        memb, styp, nmask, x, xt16, rsbuf);

    const dim3 ga(SS/64, BB*NH);
    for (int l=0; l<NL; l++){
        for (int a=0; a<4; a++){
            const int slot = l*5 + a;
            const u16* wqkv = wA + (size_t)((l*4+a)*4)*SA;
            gemm_t<<<dim3(36,16),256,0,stream>>>(xt16, wqkv, 768, 12, qk16, vt16,
                rsbuf + (size_t)slot*2048);
            attn_mfma5<<<ga,256,0,stream>>>(qk16, vt16, mbp, a, ob16);
            gemm_t64<<<dim3(12,32),256,0,stream>>>(ob16, wqkv + 3*SA, x, 768, 768, 12, 1, nullptr,
                xt16, rsbuf + (size_t)(slot+1)*2048);
        }
        gemm_gu<<<dim3(48,16),256,0,stream>>>(xt16, wGU + (size_t)l*2*SG, wGU + (size_t)l*2*SG + SG,
            rsbuf + (size_t)(l*5+4)*2048, gu16);
        gemm_t64<<<dim3(12,32),256,0,stream>>>(gu16, wD + (size_t)l*SG, x, 768, 3072, 48, 1, nullptr,
            xt16, rsbuf + (size_t)((l+1)*5)*2048);
    }

    decode2<<<NROW,256,0,stream>>>(x, gout, Wdn,bdn, Wdd,bdd, Wdb,bdb, out, xt16);
    gemm_t64<<<dim3(6,32),256,0,stream>>>(xt16, wDX, out + 3*NROW, 384, 768, 12, 2, bdtx,
        nullptr, nullptr);
}

// Round 17
// 1345.875 us; speedup vs baseline: 1.0026x; 1.0026x over previous
//
#include <hip/hip_runtime.h>
#include <hip/hip_bf16.h>
#include <cmath>
#include <stdint.h>

// Round 17 (final): revert to r15 exactly — best measured configuration (1344 us).
// GEMMs: 4-buffer / 2-ahead prefetch, one barrier per K-step. gemm_gu: 3-buf 1-ahead.
// Attention: 3-buf K/V/M, 1 barrier/chunk, bit-plane masks via m4+repack.

#define BB 2
#define SS 1024
#define DT 384
#define DM 768
#define NH 12
#define DH 64
#define DFF 3072
#define NL 4
#define NROW (BB*SS)
#define EPSF 1e-6f
#define QSC 0.1803368801111244f   // 0.125 * log2(e)

typedef unsigned short u16;
typedef unsigned char u8;
typedef unsigned int u32;
typedef __attribute__((ext_vector_type(8))) short s16x8;
typedef __attribute__((ext_vector_type(4))) float f32x4;

__device__ __forceinline__ u16 f2bu(float f){
    u32 x = __float_as_uint(f);
    u32 r = (x + 0x7fffu + ((x>>16)&1u)) >> 16;   // RNE
    return (u16)r;
}
__device__ __forceinline__ u32 pk2(float lo, float hi){
    return (u32)f2bu(lo) | ((u32)f2bu(hi)<<16);
}
__device__ __forceinline__ int swz(int row, int c){
    return (row<<6) + (((((c>>3) ^ row) & 7))<<3) + (c&7);
}
__device__ __forceinline__ float rsum16(float v){
    v += __shfl_xor(v,1); v += __shfl_xor(v,2);
    v += __shfl_xor(v,4); v += __shfl_xor(v,8);
    return v;
}
#define SBAR() __builtin_amdgcn_sched_barrier(0)
#define GLDS(src,dst) __builtin_amdgcn_global_load_lds((const __attribute__((address_space(1))) u32*)(src), (__attribute__((address_space(3))) u32*)(dst), 16, 0, 0)
#define GLDS4(src,dst) __builtin_amdgcn_global_load_lds((const __attribute__((address_space(1))) u32*)(src), (__attribute__((address_space(3))) u32*)(dst), 4, 0, 0)

// ------------------------------------------------- bool-buffer normalizer (dual)
__device__ void norm_bool_body(const void* __restrict__ src, u8* __restrict__ dst, int n)
{
    __shared__ int fl[4];
    if (threadIdx.x<4) fl[threadIdx.x]=0;
    __syncthreads();
    const u32* wsrc = (const u32*)src;
    const int nw = n/4;
    int any=0, nb=0, hi=0, lo=0;
    for (int i=threadIdx.x;i<nw;i+=blockDim.x){
        u32 v=wsrc[i];
        if (!v) continue;
        any=1;
        #pragma unroll
        for (int b=0;b<4;b++){
            u32 by=(v>>(8*b))&0xffu;
            if (by>1u) nb=1;
            if (by==1u && b!=0) hi=1;
        }
        if ((v&0xffffu)==0x3f80u) lo=1;
    }
    if (any) atomicOr(&fl[0],1);
    if (nb)  atomicOr(&fl[1],1);
    if (hi)  atomicOr(&fl[2],1);
    if (lo)  atomicOr(&fl[3],1);
    __syncthreads();
    int c;
    if (!fl[0]) c=0;
    else if (!fl[1]) c = fl[2] ? 2 : 1;
    else if (fl[3]) c = 3;
    else c = 1;
    for (int i=threadIdx.x;i<n;i+=blockDim.x){
        u8 v;
        if (c==0)      v=0;
        else if (c==1) v = (((const u32*)src)[i]!=0u);
        else if (c==2) v = (((const u8*)src)[i]!=0u);
        else           v = (((const u16*)src)[i]!=0u);
        dst[i]=v;
    }
}
__global__ void norm_bool2(const void* s0, u8* d0, const void* s1, u8* d1, int n)
{
    if (blockIdx.x==0) norm_bool_body(s0,d0,n);
    else               norm_bool_body(s1,d1,n);
}

// ------------------------------------------------- pack per-token metadata + zero rs slots
__global__ void pack_meta(const int* __restrict__ node, const int* __restrict__ colx,
                          const int* __restrict__ tbl, const u8* __restrict__ pad,
                          u32* __restrict__ pm, int n, float* __restrict__ rsz, int nz)
{
    int i = blockIdx.x*256 + threadIdx.x;
    if (i<n)
        pm[i] = (u32)(node[i]&0xff) | ((u32)(colx[i]&0xff)<<8) | ((u32)(tbl[i]&0xff)<<16) | ((u32)(pad[i]&1)<<24);
    for (int z=i; z<nz; z+=gridDim.x*256) rsz[z]=0.f;
}

// ------------------------------------------------- mask table: m4[b][k][q] bit t = mask_t(q,k)
__global__ __launch_bounds__(256) void mask4_kernel(const u32* __restrict__ pm, const int* __restrict__ f2p,
                                                    u8* __restrict__ m4)
{
    const int b = blockIdx.y, kg = blockIdx.x;
    const int t = threadIdx.x;
    __shared__ u32 qm[1024];
    __shared__ int qf[1024*5];
    for (int i=t;i<1024;i+=256) qm[i] = pm[b*SS+i];
    for (int i=t;i<5*1024;i+=256) qf[i] = f2p[b*SS*5 + i];
    __syncthreads();
    const int q0 = t*4;
    u32 qmv[4]; int qn[4]; int qfv[4][5];
    #pragma unroll
    for (int j=0;j<4;j++){
        qmv[j]=qm[q0+j]; qn[j]=(int)(qmv[j]&0xffu);
        #pragma unroll
        for (int f=0;f<5;f++) qfv[j][f]=qf[(q0+j)*5+f];
    }
    for (int kk=0;kk<16;kk++){
        const int k = kg*16+kk;
        const u32 km = qm[k];
        const int kn = (int)(km&0xffu);
        u32 outw=0;
        #pragma unroll
        for (int j=0;j<4;j++){
            const u32 qmw = qmv[j];
            const bool pv = (((qmw|km)>>24)&1u)==0u;
            u32 by=0;
            if ((((qmw^km)&0x00ffff00u)==0u) && pv) by|=1;
            if ((((qmw^km)&0xffu)==0u) && pv) by|=2;
            bool nei = (qfv[j][0]==kn)||(qfv[j][1]==kn)||(qfv[j][2]==kn)||(qfv[j][3]==kn)||(qfv[j][4]==kn)
                       ||(qn[j]==kn);
            if (nei && pv) by|=4;
            if (pv) by|=8;
            if ((q0+j)==k) by=15;
            outw |= by<<(8*j);
        }
        ((u32*)(m4 + ((size_t)b<<20) + ((size_t)k<<10)))[t] = outw;
    }
}

// ------------------------------------------------- repack m4 bytes -> 4 bit-planes
__global__ void repack_mask(const u8* __restrict__ m4, u8* __restrict__ mbp)
{
    const int gid = blockIdx.x*256 + threadIdx.x;
    const int qb = gid & 127;
    const int bk = gid >> 7;
    const u8* src = m4 + ((size_t)bk<<10) + qb*8;
    u32 lo = *(const u32*)src, hi = *(const u32*)(src+4);
    u32 out[4] = {0,0,0,0};
    #pragma unroll
    for (int j=0;j<4;j++){
        u32 b0 = (lo>>(8*j)) & 0xffu;
        u32 b1 = (hi>>(8*j)) & 0xffu;
        #pragma unroll
        for (int tt=0;tt<4;tt++){
            out[tt] |= ((b0>>tt)&1u) << j;
            out[tt] |= ((b1>>tt)&1u) << (j+4);
        }
    }
    u8* dst = mbp + (size_t)bk*512 + qb;
    #pragma unroll
    for (int tt=0;tt<4;tt++) dst[tt*128] = (u8)out[tt];
}

// ------------------------------------------------- weight f32 [K][N] -> tiled bf16 (+gamma fold)
__global__ __launch_bounds__(256) void transpose_cvt2(const float* __restrict__ src, u16* __restrict__ dst,
                                                      int K, int N, size_t dz,
                                                      const float* __restrict__ gbase, int gmode)
{
    const int z = blockIdx.z;
    src += (size_t)z*K*N;
    dst += (size_t)z*dz;
    const float* g = nullptr;
    if (gmode==1){ int m = z&3; if (m<3) g = gbase + (size_t)((z>>4)*5 + ((z>>2)&3))*768; }
    else if (gmode==2){ g = gbase + (size_t)z*5*768; }
    const int n0 = blockIdx.x*32, k0 = blockIdx.y*64;
    __shared__ float t[64][33];
    const int tid = threadIdx.x;
    const int kr = tid>>3, n4 = (tid&7)*4;
    #pragma unroll
    for (int p=0;p<2;p++){
        const int k = p*32 + kr;
        float gk = g ? g[k0+k] : 1.f;
        float4 v = *(const float4*)(src + (size_t)(k0+k)*N + n0 + n4);
        t[k][n4]=v.x*gk; t[k][n4+1]=v.y*gk; t[k][n4+2]=v.z*gk; t[k][n4+3]=v.w*gk;
    }
    __syncthreads();
    const int n = tid>>3, ks = (tid&7)*8;
    const int ng = n0 + n;
    uint4 o;
    u32* op = (u32*)&o;
    #pragma unroll
    for (int i=0;i<4;i++)
        op[i] = pk2(t[ks+2*i][n], t[ks+2*i+1][n]);
    *(uint4*)&dst[(((size_t)(ng>>7)*(K>>6) + (k0>>6))<<13) + ((ng&127)<<6) + ks] = o;
}

// ------------------------------------------------- activation f32 [M][K] -> tiled bf16 (dual src)
__global__ __launch_bounds__(256) void cvt_tiled2(const float* __restrict__ s0, u16* __restrict__ d0,
                                                  const float* __restrict__ s1, u16* __restrict__ d1, int K)
{
    const float* src = blockIdx.y ? s1 : s0;
    u16* dst = blockIdx.y ? d1 : d0;
    const int gid = blockIdx.x*256 + threadIdx.x;
    const int base = gid*8;
    const int row = base / K, col = base - row*K;
    float4 a = *(const float4*)(src + base);
    float4 b = *(const float4*)(src + base + 4);
    uint4 o;
    o.x = pk2(a.x,a.y); o.y = pk2(a.z,a.w);
    o.z = pk2(b.x,b.y); o.w = pk2(b.z,b.w);
    *(uint4*)&dst[(((size_t)(row>>7)*(K>>6) + (col>>6))<<13) + ((row&127)<<6) + (col&63)] = o;
}

// ------------------------------------------------- BM=128 GEMM (qkv): 4-buf, 2-ahead, 1 barrier/step
__device__ __forceinline__ void stage3(const u16* aT, const u16* bT, int cb, int brow,
                                       u16* la, u16* lb, int w, int l)
{
    #pragma unroll
    for (int p=0;p<2;p++){
        const int q = p*256 + w*64 + l;
        const int row = q>>2, u = q&3;
        const int so = row*64 + cb + (((u ^ ((row>>1)&3))&3)<<3);
        GLDS(aT+so, la + p*2048 + w*512);
    }
    {
        const int q = w*64 + l;
        const int row = q>>2, u = q&3;
        const int so = (brow+row)*64 + cb + (((u ^ ((row>>1)&3))&3)<<3);
        GLDS(bT+so, lb + w*512);
    }
}

__global__ __launch_bounds__(256,3) void gemm_t(
    const u16* __restrict__ At, const u16* __restrict__ Bt,
    int K, int AMS, u16* __restrict__ qk16, u16* __restrict__ vt16,
    const float* __restrict__ rs_in)
{
    __shared__ u16 lds[4][6144];   // 48KB
    const int tid = threadIdx.x;
    const int lane = tid & 63, w = tid >> 6;
    const int cg = lane >> 4, cl = lane & 15;
    const int NT = K >> 5;
    const int n0 = blockIdx.x*64;
    const int brow = n0 & 64;
    const size_t bNb = (size_t)(n0>>7)*(K>>6);

    const u16* aB = At + ((size_t)blockIdx.y * AMS << 13);
    const u16* bB = Bt + (bNb << 13);

    f32x4 acc[2][4];
    #pragma unroll
    for (int i=0;i<2;i++)
        #pragma unroll
        for (int j=0;j<4;j++) acc[i][j] = (f32x4){0.f,0.f,0.f,0.f};

    stage3(aB, bB, 0,  brow, &lds[0][0], &lds[0][4096], w, lane);             // tile 0
    stage3(aB, bB, 32, brow, &lds[1][0], &lds[1][4096], w, lane);             // tile 1

    for (int kt=0; kt<NT; kt++){
        const int buf = kt & 3;
        if (kt+2 < NT){
            const int k2 = kt+2;
            stage3(aB + ((size_t)(k2>>1)<<13), bB + ((size_t)(k2>>1)<<13),
                   (k2&1)<<5, brow, &lds[k2&3][0], &lds[k2&3][4096], w, lane);
            asm volatile("s_waitcnt vmcnt(6)" ::: "memory");
        } else if (kt+1 < NT){
            asm volatile("s_waitcnt vmcnt(3)" ::: "memory");
        } else {
            asm volatile("s_waitcnt vmcnt(0)" ::: "memory");
        }
        SBAR(); __builtin_amdgcn_s_barrier(); SBAR();
        s16x8 af[2], bf[4];
        #pragma unroll
        for (int mt=0;mt<2;mt++){
            const int ra = w*32 + mt*16 + cl;
            af[mt] = *(const s16x8*)&lds[buf][ra*32 + (((cg ^ ((ra>>1)&3))&3)<<3)];
        }
        #pragma unroll
        for (int nt=0;nt<4;nt++){
            const int rb = nt*16 + cl;
            bf[nt] = *(const s16x8*)&lds[buf][4096 + rb*32 + (((cg ^ ((rb>>1)&3))&3)<<3)];
        }
        #pragma unroll
        for (int mt=0;mt<2;mt++)
            #pragma unroll
            for (int nt=0;nt<4;nt++)
                acc[mt][nt] = __builtin_amdgcn_mfma_f32_16x16x32_bf16(af[mt], bf[nt], acc[mt][nt], 0,0,0);
    }

    const int m0 = blockIdx.y*128;
    #pragma unroll
    for (int mt=0;mt<2;mt++){
        const int grow0 = m0 + w*32 + mt*16 + cg*4;
        float rr[4];
        #pragma unroll
        for (int j=0;j<4;j++) rr[j] = rsqrtf(rs_in[grow0+j]*(1.f/768.f) + EPSF);
        #pragma unroll
        for (int nt=0;nt<4;nt++){
            const int col = n0 + nt*16 + cl;
            if (col < 768){
                #pragma unroll
                for (int j=0;j<4;j++)
                    qk16[(size_t)(grow0+j)*1536 + col] = f2bu(acc[mt][nt][j]*rr[j]*QSC);
            } else if (col < 1536){
                #pragma unroll
                for (int j=0;j<4;j++)
                    qk16[(size_t)(grow0+j)*1536 + col] = f2bu(acc[mt][nt][j]*rr[j]);
            } else {
                const int b = grow0>>10, s0 = grow0&1023;
                const int dhg = col - 1536;
                uint2 o;
                o.x = pk2(acc[mt][nt][0]*rr[0], acc[mt][nt][1]*rr[1]);
                o.y = pk2(acc[mt][nt][2]*rr[2], acc[mt][nt][3]*rr[3]);
                *(uint2*)(vt16 + ((size_t)(b*768 + dhg)<<10) + s0) = o;
            }
        }
    }
}

// ------------------------------------------------- fused gate-up-silu GEMM: 3-buf, 1-ahead
__global__ __launch_bounds__(256,3) void gemm_gu(
    const u16* __restrict__ At, const u16* __restrict__ Bg, const u16* __restrict__ Bu,
    const float* __restrict__ rs_in, u16* __restrict__ o16)
{
    __shared__ u16 lds[3][8192];
    const int tid = threadIdx.x;
    const int lane = tid & 63, w = tid >> 6;
    const int cg = lane >> 4, cl = lane & 15;
    const int NT = 24;
    const int n0 = blockIdx.x*64;
    const int brow = n0 & 64;
    const size_t bNb = (size_t)(n0>>7)*12;

    const u16* aB = At + ((size_t)blockIdx.y * 12 << 13);
    const u16* gB = Bg + (bNb << 13);
    const u16* uB = Bu + (bNb << 13);

    f32x4 accg[2][4], accu[2][4];
    #pragma unroll
    for (int i=0;i<2;i++)
        #pragma unroll
        for (int j=0;j<4;j++){ accg[i][j] = (f32x4){0.f,0.f,0.f,0.f}; accu[i][j] = (f32x4){0.f,0.f,0.f,0.f}; }

    #define STAGE_GU(kt2, cb, buf) { \
        const u16* a_ = aB + ((size_t)(kt2)<<13); \
        const u16* g_ = gB + ((size_t)(kt2)<<13); \
        const u16* u_ = uB + ((size_t)(kt2)<<13); \
        _Pragma("unroll") \
        for (int p=0;p<2;p++){ \
            const int q = p*256 + w*64 + lane; \
            const int row = q>>2, uu = q&3; \
            const int so = row*64 + (cb) + (((uu ^ ((row>>1)&3))&3)<<3); \
            GLDS(a_+so, &lds[buf][0] + p*2048 + w*512); \
        } \
        { \
            const int q = w*64 + lane; \
            const int row = q>>2, uu = q&3; \
            const int so = (brow+row)*64 + (cb) + (((uu ^ ((row>>1)&3))&3)<<3); \
            GLDS(g_+so, &lds[buf][4096] + w*512); \
            GLDS(u_+so, &lds[buf][6144] + w*512); \
        } }

    STAGE_GU(0, 0, 0);

    for (int kt=0; kt<NT; kt++){
        const int buf = kt % 3;
        if (kt+1 < NT){
            const int k1 = kt+1;
            STAGE_GU(k1>>1, (k1&1)<<5, k1%3);
            asm volatile("s_waitcnt vmcnt(4)" ::: "memory");
        } else {
            asm volatile("s_waitcnt vmcnt(0)" ::: "memory");
        }
        SBAR(); __builtin_amdgcn_s_barrier(); SBAR();
        s16x8 af[2], bg[4], bu[4];
        #pragma unroll
        for (int mt=0;mt<2;mt++){
            const int ra = w*32 + mt*16 + cl;
            af[mt] = *(const s16x8*)&lds[buf][ra*32 + (((cg ^ ((ra>>1)&3))&3)<<3)];
        }
        #pragma unroll
        for (int nt=0;nt<4;nt++){
            const int rb = nt*16 + cl;
            const int sw = (((cg ^ ((rb>>1)&3))&3)<<3);
            bg[nt] = *(const s16x8*)&lds[buf][4096 + rb*32 + sw];
            bu[nt] = *(const s16x8*)&lds[buf][6144 + rb*32 + sw];
        }
        #pragma unroll
        for (int mt=0;mt<2;mt++)
            #pragma unroll
            for (int nt=0;nt<4;nt++){
                accg[mt][nt] = __builtin_amdgcn_mfma_f32_16x16x32_bf16(af[mt], bg[nt], accg[mt][nt], 0,0,0);
                accu[mt][nt] = __builtin_amdgcn_mfma_f32_16x16x32_bf16(af[mt], bu[nt], accu[mt][nt], 0,0,0);
            }
    }

    const int m0 = blockIdx.y*128;
    #pragma unroll
    for (int mt=0;mt<2;mt++){
        const int grow0 = m0 + w*32 + mt*16 + cg*4;
        float rr[4];
        #pragma unroll
        for (int j=0;j<4;j++) rr[j] = rsqrtf(rs_in[grow0+j]*(1.f/768.f) + EPSF);
        #pragma unroll
        for (int nt=0;nt<4;nt++){
            const int col = n0 + nt*16 + cl;
            const size_t tb = (((size_t)(grow0>>7)*48 + (col>>6))<<13) + (col&63);
            #pragma unroll
            for (int j=0;j<4;j++){
                float g = accg[mt][nt][j]*rr[j];
                float u = accu[mt][nt][j]*rr[j];
                float s = g/(1.f+__expf(-g))*u;
                o16[tb + (((grow0+j)&127)<<6)] = f2bu(s);
            }
        }
    }
}

// ------------------------------------------------- BM=64 GEMM: 4-buf, 2-ahead, 1 barrier/step
__device__ __forceinline__ void stage64(const u16* aT, int arow, const u16* bT, int brow, int cb,
                                        u16* la, u16* lb, int w, int l)
{
    const int q = w*64 + l;
    const int row = q>>2, u = q&3;
    const int sw = (((u ^ ((row>>1)&3))&3)<<3);
    GLDS(aT + (arow+row)*64 + cb + sw, la + w*512);
    GLDS(bT + (brow+row)*64 + cb + sw, lb + w*512);
}

__global__ __launch_bounds__(256,4) void gemm_t64(
    const u16* __restrict__ At, const u16* __restrict__ Bt, float* __restrict__ C,
    int N, int K, int AMS, int flags, const float* __restrict__ bias,
    u16* __restrict__ o16, float* __restrict__ rs_out)
{
    __shared__ u16 lds[4][4096];   // 32KB
    const int tid = threadIdx.x;
    const int lane = tid & 63, w = tid >> 6;
    const int cg = lane >> 4, cl = lane & 15;
    const int NT = K >> 5;
    const int n0 = blockIdx.x*64;
    const int m0 = blockIdx.y*64;
    const int brow = n0 & 64, arow = m0 & 64;

    const u16* aB = At + ((size_t)(m0>>7) * AMS << 13);
    const u16* bB = Bt + ((size_t)(n0>>7) * (K>>6) << 13);

    f32x4 acc[4];
    #pragma unroll
    for (int j=0;j<4;j++) acc[j] = (f32x4){0.f,0.f,0.f,0.f};

    stage64(aB, arow, bB, brow, 0,  &lds[0][0], &lds[0][2048], w, lane);
    stage64(aB, arow, bB, brow, 32, &lds[1][0], &lds[1][2048], w, lane);

    for (int kt=0; kt<NT; kt++){
        const int buf = kt & 3;
        if (kt+2 < NT){
            const int k2 = kt+2;
            stage64(aB + ((size_t)(k2>>1)<<13), arow, bB + ((size_t)(k2>>1)<<13), brow,
                    (k2&1)<<5, &lds[k2&3][0], &lds[k2&3][2048], w, lane);
            asm volatile("s_waitcnt vmcnt(4)" ::: "memory");
        } else if (kt+1 < NT){
            asm volatile("s_waitcnt vmcnt(2)" ::: "memory");
        } else {
            asm volatile("s_waitcnt vmcnt(0)" ::: "memory");
        }
        SBAR(); __builtin_amdgcn_s_barrier(); SBAR();
        const int ra = w*16 + cl;
        s16x8 af = *(const s16x8*)&lds[buf][ra*32 + (((cg ^ ((ra>>1)&3))&3)<<3)];
        s16x8 bf[4];
        #pragma unroll
        for (int nt=0;nt<4;nt++){
            const int rb = nt*16 + cl;
            bf[nt] = *(const s16x8*)&lds[buf][2048 + rb*32 + (((cg ^ ((rb>>1)&3))&3)<<3)];
        }
        #pragma unroll
        for (int nt=0;nt<4;nt++)
            acc[nt] = __builtin_amdgcn_mfma_f32_16x16x32_bf16(af, bf[nt], acc[nt], 0,0,0);
    }

    const int grow0 = m0 + w*16 + cg*4;
    const bool do_acc = (flags&1), do_bias = (flags&2);
    float tmp[4][4];
    #pragma unroll
    for (int nt=0;nt<4;nt++){
        const int col = n0 + nt*16 + cl;
        float bv = do_bias ? bias[col] : 0.f;
        #pragma unroll
        for (int j=0;j<4;j++){
            float v = acc[nt][j] + bv;
            float* cp = C + (size_t)(grow0+j)*N + col;
            if (do_acc) v += *cp;
            *cp = v;
            tmp[nt][j] = v;
        }
    }
    if (o16){
        #pragma unroll
        for (int nt=0;nt<4;nt++){
            const int col = n0 + nt*16 + cl;
            const size_t tb = (((size_t)(grow0>>7)*12 + (col>>6))<<13) + (col&63);
            #pragma unroll
            for (int j=0;j<4;j++)
                o16[tb + (((grow0+j)&127)<<6)] = f2bu(tmp[nt][j]);
        }
    }
    if (rs_out){
        #pragma unroll
        for (int j=0;j<4;j++){
            float s = tmp[0][j]*tmp[0][j] + tmp[1][j]*tmp[1][j]
                    + tmp[2][j]*tmp[2][j] + tmp[3][j]*tmp[3][j];
            s = rsum16(s);
            if (cl==0) atomicAdd(rs_out + grow0 + j, s);
        }
    }
}

// ------------------------------------------------- MFMA flash attention: 3-buf K/V/M, 1 barrier/chunk
__global__ __launch_bounds__(256,2) void attn_mfma5(
    const u16* __restrict__ qk16, const u16* __restrict__ vt16,
    const u8* __restrict__ mbp, int mt,
    u16* __restrict__ ob16)
{
    const int bh = blockIdx.y;
    const int b = bh / NH, h = bh % NH;
    const int q0 = blockIdx.x * 64;
    const int tid = threadIdx.x;
    const int w = tid>>6, lane = tid&63, cg = lane>>4, cl = lane&15;
    const int srow = lane>>3;
    const int sseg = (lane&7) ^ srow;

    __shared__ u16 Ks[3][4096], Vt[3][4096], Ps[4096];
    __shared__ u8 Ms[3][512];

    s16x8 qa0, qa1;
    {
        const u16* qrow = qk16 + (size_t)(b*SS+q0 + w*16 + cl)*1536 + h*64;
        qa0 = *(const s16x8*)(qrow + cg*8);
        qa1 = *(const s16x8*)(qrow + 32 + cg*8);
        asm volatile("" :: "v"(*(const f32x4*)&qa0), "v"(*(const f32x4*)&qa1));
    }

    const u16* kbase = qk16 + (size_t)(b*SS)*1536 + 768 + h*64;
    const u16* vbase = vt16 + ((size_t)(b*768 + h*64)<<10);
    const u8* mrow0 = mbp + ((size_t)(b<<10))*512 + mt*128 + (q0>>3);

    #pragma unroll
    for (int p=0;p<2;p++){
        const int row = p*32 + w*8 + srow;
        GLDS(kbase + (size_t)row*1536 + sseg*8, Ks[0] + p*2048 + w*512);
        GLDS(vbase + ((size_t)row<<10) + sseg*8, Vt[0] + p*2048 + w*512);
    }
    if (lane < 32){
        const int krow = w*16 + (lane>>1);
        GLDS4(mrow0 + (size_t)krow*512 + (lane&1)*4, Ms[0] + w*128);
    }

    f32x4 o[4];
    #pragma unroll
    for (int nt=0;nt<4;nt++) o[nt] = (f32x4){0.f,0.f,0.f,0.f};
    float lsum[4] = {0.f,0.f,0.f,0.f};

    for (int kc=0;kc<16;kc++){
        const int buf = kc % 3;
        if (kc < 15){
            const int nb = (kc+1) % 3;
            const int kn0 = kc*64 + 64;
            #pragma unroll
            for (int p=0;p<2;p++){
                const int row = p*32 + w*8 + srow;
                GLDS(kbase + (size_t)(kn0+row)*1536 + sseg*8, Ks[nb] + p*2048 + w*512);
                GLDS(vbase + ((size_t)row<<10) + kn0 + sseg*8, Vt[nb] + p*2048 + w*512);
            }
            if (lane < 32){
                const int krow = kn0 + w*16 + (lane>>1);
                GLDS4(mrow0 + (size_t)krow*512 + (lane&1)*4, Ms[nb] + w*128);
            }
            asm volatile("s_waitcnt vmcnt(5)" ::: "memory");
        } else {
            asm volatile("s_waitcnt vmcnt(0)" ::: "memory");
        }
        SBAR(); __builtin_amdgcn_s_barrier(); SBAR();

        f32x4 sc[4];
        #pragma unroll
        for (int nt=0;nt<4;nt++) sc[nt] = (f32x4){0.f,0.f,0.f,0.f};
        __builtin_amdgcn_s_setprio(1);
        #pragma unroll
        for (int nt=0;nt<4;nt++){
            s16x8 kb0 = *(const s16x8*)&Ks[buf][swz(nt*16+cl, cg*8)];
            sc[nt] = __builtin_amdgcn_mfma_f32_16x16x32_bf16(qa0, kb0, sc[nt], 0,0,0);
        }
        #pragma unroll
        for (int nt=0;nt<4;nt++){
            s16x8 kb1 = *(const s16x8*)&Ks[buf][swz(nt*16+cl, 32+cg*8)];
            sc[nt] = __builtin_amdgcn_mfma_f32_16x16x32_bf16(qa1, kb1, sc[nt], 0,0,0);
        }
        __builtin_amdgcn_s_setprio(0);

        float pP[4][4];
        const int qb = 2*w + (cg>>1);
        const int bsh = (cg&1)*4;
        #pragma unroll
        for (int nt=0;nt<4;nt++){
            const u32 mrow = Ms[buf][(nt*16+cl)*8 + qb];
            #pragma unroll
            for (int j=0;j<4;j++){
                float pe = exp2f(fminf(sc[nt][j], 100.f));
                pe = ((mrow >> (bsh+j)) & 1u) ? pe : 0.f;
                pP[nt][j] = pe;
                lsum[j] += pe;
            }
        }

        #pragma unroll
        for (int nt=0;nt<4;nt++)
            #pragma unroll
            for (int j=0;j<4;j++)
                Ps[swz(w*16+cg*4+j, nt*16+cl)] = f2bu(pP[nt][j]);

        __builtin_amdgcn_s_setprio(1);
        #pragma unroll
        for (int ks=0;ks<2;ks++){
            s16x8 pa = *(const s16x8*)&Ps[swz(w*16+cl, ks*32+cg*8)];
            #pragma unroll
            for (int nt=0;nt<4;nt++){
                s16x8 vb = *(const s16x8*)&Vt[buf][swz(nt*16+cl, ks*32+cg*8)];
                o[nt] = __builtin_amdgcn_mfma_f32_16x16x32_bf16(pa, vb, o[nt], 0,0,0);
            }
        }
        __builtin_amdgcn_s_setprio(0);
    }

    #pragma unroll
    for (int j=0;j<4;j++){
        const float inv = 1.f/rsum16(lsum[j]);
        const int row = b*SS + q0 + w*16 + cg*4 + j;
        const size_t rb = ((size_t)(row>>7)*12 + h)*8192 + ((row&127)<<6);
        #pragma unroll
        for (int nt=0;nt<4;nt++)
            ob16[rb + nt*16 + cl] = f2bu(o[nt][j]*inv);
    }
}

// ------------------------------------------------- encode fuse
__global__ __launch_bounds__(256) void fuse_encode(
    const float* __restrict__ cnbuf, const float* __restrict__ textbuf,
    const float* __restrict__ numv, const float* __restrict__ dtv, const float* __restrict__ boolv,
    const float* __restrict__ Wnum, const float* __restrict__ bnum,
    const float* __restrict__ Wdt, const float* __restrict__ bdt,
    const float* __restrict__ Wbool, const float* __restrict__ bbool,
    const float* __restrict__ gcn, const float* __restrict__ gnum, const float* __restrict__ gtext,
    const float* __restrict__ gdt, const float* __restrict__ gbool,
    const float* __restrict__ memb, const int* __restrict__ stypes, const u8* __restrict__ masks,
    float* __restrict__ x, u16* __restrict__ xt16, float* __restrict__ rs0)
{
    const int row = blockIdx.x;
    const int t = threadIdx.x;
    __shared__ float red[256];

    float cn3[3]; float ss=0.f;
    #pragma unroll
    for (int j=0;j<3;j++){
        cn3[j] = cnbuf[(size_t)row*DM + t + j*256];
        ss += cn3[j]*cn3[j];
    }
    red[t]=ss; __syncthreads();
    for (int s=128;s>0;s>>=1){ if(t<s) red[t]+=red[t+s]; __syncthreads(); }
    {
        float r = rsqrtf(red[0]/(float)DM + EPSF);
        #pragma unroll
        for (int j=0;j<3;j++) cn3[j] *= r*gcn[t+j*256];
    }
    __syncthreads();

    const int st = stypes[row];
    float val[3]; ss=0.f;
    if (st==1){
        #pragma unroll
        for (int j=0;j<3;j++){
            val[j] = textbuf[(size_t)row*DM + t + j*256];
            ss += val[j]*val[j];
        }
    } else {
        const float* Wp = (st==0)?Wnum:((st==2)?Wdt:Wbool);
        const float* bp = (st==0)?bnum:((st==2)?bdt:bbool);
        const float* vp = (st==0)?numv:((st==2)?dtv:boolv);
        float v = vp[row];
        #pragma unroll
        for (int j=0;j<3;j++){
            int e=t+j*256;
            val[j] = v*Wp[e] + bp[e];
            ss += val[j]*val[j];
        }
    }
    red[t]=ss; __syncthreads();
    for (int s=128;s>0;s>>=1){ if(t<s) red[t]+=red[t+s]; __syncthreads(); }
    const float* gp = (st==0)?gnum:((st==1)?gtext:((st==2)?gdt:gbool));
    float r2 = rsqrtf(red[0]/(float)DM + EPSF);
    bool mk = masks[row]!=0;
    float xv[3]; float sx=0.f;
    #pragma unroll
    for (int j=0;j<3;j++){
        int e=t+j*256;
        float vv = val[j]*r2*gp[e];
        if (mk) vv = memb[st*DM+e];
        xv[j] = vv + cn3[j];
        x[(size_t)row*DM+e] = xv[j];
        sx += xv[j]*xv[j];
    }
    __syncthreads();
    red[t]=sx; __syncthreads();
    for (int s=128;s>0;s>>=1){ if(t<s) red[t]+=red[t+s]; __syncthreads(); }
    if (t==0) rs0[row] = red[0];
    const size_t mb = (size_t)(row>>7)*12;
    const int rr = (row&127)<<6;
    #pragma unroll
    for (int j=0;j<3;j++){
        const int c = t + j*256;
        xt16[((mb + (c>>6))<<13) + rr + (c&63)] = f2bu(xv[j]);
    }
}

// ------------------------------------------------- final rms + 3 scalar heads; h -> tiled bf16
__global__ __launch_bounds__(256) void decode2(
    const float* __restrict__ x, const float* __restrict__ gout,
    const float* __restrict__ Wn, const float* __restrict__ bn,
    const float* __restrict__ Wd, const float* __restrict__ bd,
    const float* __restrict__ Wb, const float* __restrict__ bb,
    float* __restrict__ out, u16* __restrict__ h16)
{
    const int row = blockIdx.x;
    const int t = threadIdx.x;
    __shared__ float h[DM];
    __shared__ float red[256];
    const float* xr = x + (size_t)row*DM;
    float v0=xr[t], v1=xr[t+256], v2=xr[t+512];
    red[t]=v0*v0+v1*v1+v2*v2; __syncthreads();
    for (int s=128;s>0;s>>=1){ if(t<s) red[t]+=red[t+s]; __syncthreads(); }
    float r = rsqrtf(red[0]/(float)DM + EPSF);
    float h0 = v0*r*gout[t], h1 = v1*r*gout[t+256], h2 = v2*r*gout[t+512];
    h[t]=h0; h[t+256]=h1; h[t+512]=h2;
    const size_t mb = (size_t)(row>>7)*12;
    const int rr = (row&127)<<6;
    #pragma unroll
    for (int j=0;j<3;j++){
        const int c = t + j*256;
        const float v = (j==0?h0:(j==1?h1:h2));
        h16[((mb + (c>>6))<<13) + rr + (c&63)] = f2bu(v);
    }
    __syncthreads();

    float pn=0.f,pd=0.f,pb=0.f;
    for (int k=t;k<DM;k+=256){ float hv=h[k]; pn+=hv*Wn[k]; pd+=hv*Wd[k]; pb+=hv*Wb[k]; }
    red[t]=pn; __syncthreads();
    for (int s=128;s>0;s>>=1){ if(t<s) red[t]+=red[t+s]; __syncthreads(); }
    float tn=red[0]; __syncthreads();
    red[t]=pd; __syncthreads();
    for (int s=128;s>0;s>>=1){ if(t<s) red[t]+=red[t+s]; __syncthreads(); }
    float td=red[0]; __syncthreads();
    red[t]=pb; __syncthreads();
    for (int s=128;s>0;s>>=1){ if(t<s) red[t]+=red[t+s]; __syncthreads(); }
    float tb=red[0];
    if (t==0){
        out[row]          = tn + bn[0];
        out[NROW + row]   = td + bd[0];
        out[2*NROW + row] = tb + bb[0];
    }
}

// ---------------------------------------------------------------- launcher
extern "C" void kernel_launch(void* const* d_in, const int* in_sizes, int n_in,
                              void* d_out, int out_size, void* d_ws, size_t ws_size,
                              hipStream_t stream)
{
    const float* numv   = (const float*)d_in[0];
    const float* dtval  = (const float*)d_in[1];
    const float* boolv  = (const float*)d_in[2];
    const float* textv  = (const float*)d_in[3];
    const float* cnamev = (const float*)d_in[4];
    const float* Wcn=(const float*)d_in[5];  const float* bcn=(const float*)d_in[6];
    const float* Wnum=(const float*)d_in[7]; const float* bnum=(const float*)d_in[8];
    const float* Wtext=(const float*)d_in[9];const float* btext=(const float*)d_in[10];
    const float* Wdt=(const float*)d_in[11]; const float* bdt=(const float*)d_in[12];
    const float* Wbool=(const float*)d_in[13];const float* bbool=(const float*)d_in[14];
    const float* gcn=(const float*)d_in[15]; const float* gnum=(const float*)d_in[16];
    const float* gtext=(const float*)d_in[17];const float* gdt=(const float*)d_in[18];
    const float* gbool=(const float*)d_in[19];
    const float* memb=(const float*)d_in[20];
    const float* norms_all=(const float*)d_in[21];
    const float* attw_all=(const float*)d_in[22];
    const float* up_all=(const float*)d_in[23];
    const float* gate_all=(const float*)d_in[24];
    const float* down_all=(const float*)d_in[25];
    const float* gout=(const float*)d_in[26];
    const float* Wdn=(const float*)d_in[27]; const float* bdn=(const float*)d_in[28];
    const float* Wdd=(const float*)d_in[29]; const float* bdd=(const float*)d_in[30];
    const float* Wdb=(const float*)d_in[31]; const float* bdb=(const float*)d_in[32];
    const float* Wdtx=(const float*)d_in[33];const float* bdtx=(const float*)d_in[34];
    const int* node=(const int*)d_in[35];
    const int* tbl =(const int*)d_in[36];
    const int* colx=(const int*)d_in[37];
    const int* f2p =(const int*)d_in[38];
    const int* styp=(const int*)d_in[39];

    const size_t SA = (size_t)768*768;
    const size_t SG = (size_t)768*3072;
    const size_t SC = (size_t)384*768;
    const size_t NX = (size_t)NROW*DM;

    u8* base = (u8*)d_ws;
    float* x  = (float*)base;
    u16* xt16 = (u16*)(base + 6291456);
    u16* ob16 = (u16*)(base + 9437184);
    u16* qk16 = (u16*)(base + 12582912);
    u16* vt16 = (u16*)(base + 18874368);
    u16* gu16 = (u16*)(base + 22020096);
    u16* wA   = (u16*)(base + 47185920);
    u16* wGU  = wA + 64*SA;
    u16* wD   = wGU + 8*SG;
    u16* wCN  = wD + 4*SG;
    u16* wTX  = wCN + SC;
    u16* wDX  = wTX + SC;
    u8* nmask = (u8*)(wDX + SC);
    u8* npad  = nmask + NROW;
    u32* pmeta = (u32*)(npad + NROW + 64);
    float* rsbuf = (float*)(pmeta + NROW);     // 21 slots x 2048
    u8* m4 = (u8*)(rsbuf + 21*2048);           // 2 MB
    u8* mbp = m4 + ((size_t)2<<20);            // 1 MB bit-planes

    // encode-phase aliases
    u16* cnT16   = qk16;
    u16* textT16 = vt16;
    float* cnbuf   = (float*)gu16;
    float* textbuf = cnbuf + NX;

    float* out = (float*)d_out;

    norm_bool2<<<2,256,0,stream>>>(d_in[40], nmask, d_in[41], npad, NROW);
    pack_meta<<<8,256,0,stream>>>(node, colx, tbl, npad, pmeta, NROW, rsbuf, 21*2048);
    mask4_kernel<<<dim3(64,2),256,0,stream>>>(pmeta, f2p, m4);
    repack_mask<<<1024,256,0,stream>>>(m4, mbp);

    // weight prep (tiled bf16; gamma folded)
    transpose_cvt2<<<dim3(24,12,64),256,0,stream>>>(attw_all, wA, 768, 768, SA, norms_all, 1);
    transpose_cvt2<<<dim3(96,12,4),256,0,stream>>>(gate_all, wGU,      768, 3072, 2*SG, norms_all + 4*768, 2);
    transpose_cvt2<<<dim3(96,12,4),256,0,stream>>>(up_all,   wGU + SG, 768, 3072, 2*SG, norms_all + 4*768, 2);
    transpose_cvt2<<<dim3(24,48,4),256,0,stream>>>(down_all, wD, 3072, 768, SG, nullptr, 0);
    transpose_cvt2<<<dim3(24,6,1),256,0,stream>>>(Wcn,   wCN, 384, 768, 0, nullptr, 0);
    transpose_cvt2<<<dim3(24,6,1),256,0,stream>>>(Wtext, wTX, 384, 768, 0, nullptr, 0);
    transpose_cvt2<<<dim3(12,12,1),256,0,stream>>>(Wdtx, wDX, 768, 384, 0, nullptr, 0);

    // encode
    cvt_tiled2<<<dim3(384,2),256,0,stream>>>(cnamev, cnT16, textv, textT16, 384);
    gemm_t64<<<dim3(12,32),256,0,stream>>>(cnT16,   wCN, cnbuf,   768, 384, 6, 2, bcn,   nullptr, nullptr);
    gemm_t64<<<dim3(12,32),256,0,stream>>>(textT16, wTX, textbuf, 768, 384, 6, 2, btext, nullptr, nullptr);
    fuse_encode<<<NROW,256,0,stream>>>(cnbuf, textbuf, numv, dtval, boolv,
        Wnum,bnum,Wdt,bdt,Wbool,bbool, gcn,gnum,gtext,gdt,gbool,
        memb, styp, nmask, x, xt16, rsbuf);

    const dim3 ga(SS/64, BB*NH);
    for (int l=0; l<NL; l++){
        for (int a=0; a<4; a++){
            const int slot = l*5 + a;
            const u16* wqkv = wA + (size_t)((l*4+a)*4)*SA;
            gemm_t<<<dim3(36,16),256,0,stream>>>(xt16, wqkv, 768, 12, qk16, vt16,
                rsbuf + (size_t)slot*2048);
            attn_mfma5<<<ga,256,0,stream>>>(qk16, vt16, mbp, a, ob16);
            gemm_t64<<<dim3(12,32),256,0,stream>>>(ob16, wqkv + 3*SA, x, 768, 768, 12, 1, nullptr,
                xt16, rsbuf + (size_t)(slot+1)*2048);
        }
        gemm_gu<<<dim3(48,16),256,0,stream>>>(xt16, wGU + (size_t)l*2*SG, wGU + (size_t)l*2*SG + SG,
            rsbuf + (size_t)(l*5+4)*2048, gu16);
        gemm_t64<<<dim3(12,32),256,0,stream>>>(gu16, wD + (size_t)l*SG, x, 768, 3072, 48, 1, nullptr,
            xt16, rsbuf + (size_t)((l+1)*5)*2048);
    }

    decode2<<<NROW,256,0,stream>>>(x, gout, Wdn,bdn, Wdd,bdd, Wdb,bdb, out, xt16);
    gemm_t64<<<dim3(6,32),256,0,stream>>>(xt16, wDX, out + 3*NROW, 384, 768, 12, 2, bdtx,
        nullptr, nullptr);
}